// Round 3
// baseline (967.891 us; speedup 1.0000x reference)
//
#include <hip/hip_runtime.h>
#include <math.h>

#define D_MODEL 2048
#define NEXP    64
#define NROWS   32768
#define BM      64                 // rows per block (= lanes per wave)
#define BK      64                 // k per chunk
#define NCHUNK  (D_MODEL / BK)     // 32
#define NG      (BK / 4)           // 16 granules (16B) per chunk row

// async global->LDS, 16B per lane; LDS dest = wave-uniform base + lane*16
__device__ __forceinline__ void stage16(const float* gsrc, void* lds_base) {
    __builtin_amdgcn_global_load_lds(
        (const __attribute__((address_space(1))) void*)gsrc,
        (__attribute__((address_space(3))) void*)lds_base,
        16, 0, 0);
}

// Block = 256 threads = 4 waves. Lane l owns row r0+l; wave w owns experts
// [16w,16w+16). x: staged granule-major in LDS (1 ds_read_b128 per lane per
// 4k -> LDS pipe ~37%). W: wave-uniform-address VECTOR loads (vmcnt path,
// L1/L2-resident 512KB; NOT s_load -- round 1 showed SMEM streaming stalls
// ~900cyc/g-step on K$ misses + lgkmcnt(0) coupling with ds_read).
__global__ __launch_bounds__(256, 2) void router_kernel(
    const float* __restrict__ x,      // [NROWS, D_MODEL]
    const float* __restrict__ gw,     // [NEXP, D_MODEL]
    const float* __restrict__ bias,   // [NEXP]
    float* __restrict__ out)          // [NROWS*2 weights][NROWS*2 idx-as-float]
{
    __shared__ alignas(16) float4 xsg[2][NG][BM];   // 32 KB, granule-major
    __shared__ alignas(16) float  logits[BM][68];   // stride 68: scan-friendly

    const int t    = threadIdx.x;
    const int lane = t & 63;
    const int wu   = __builtin_amdgcn_readfirstlane(t >> 6); // uniform: staging/epilogue
    const int r0   = blockIdx.x * BM;

    // Expert base for this wave. Laundered through a VGPR constraint so the
    // compiler treats it as divergent -> W loads stay global_load (VMEM),
    // never s_load. (All lanes hold the same value; HW merges the requests.)
    int ebase = (t >> 6) << 4;
    asm volatile("" : "+v"(ebase));

    const float* xrow = x + (size_t)(r0 + lane) * D_MODEL;

    // 16 per-expert W pointers kept in VGPR pairs; per-g offsets fold into
    // the 13-bit immediate (g*16B <= 240), no per-load address VALU.
    const float* wp[16];
#pragma unroll
    for (int j = 0; j < 16; ++j)
        wp[j] = gw + (size_t)(ebase + j) * D_MODEL;

    float acc[16];
#pragma unroll
    for (int j = 0; j < 16; ++j) acc[j] = 0.f;

    // prologue: stage chunk 0 into buffer 0 (wave wu stages granules i*4+wu)
#pragma unroll
    for (int i = 0; i < 4; ++i) {
        const int q = i * 4 + wu;
        stage16(xrow + q * 4, &xsg[0][q][0]);
    }
    __syncthreads();   // barrier drain (vmcnt 0) completes the stage

    for (int c = 0; c < NCHUNK; ++c) {
        const int cur = c & 1;
        // issue next chunk's async x-stage; completes by end-of-iter barrier
        if (c + 1 < NCHUNK) {
            const float* src = xrow + (c + 1) * BK;
#pragma unroll
            for (int i = 0; i < 4; ++i) {
                const int q = i * 4 + wu;
                stage16(src + q * 4, &xsg[cur ^ 1][q][0]);
            }
        }
#pragma unroll
        for (int g = 0; g < NG; ++g) {
            // own row's next 4 ks: one conflict-free b128 (lane i -> byte i*16)
            const float4 xa = xsg[cur][g][lane];
#pragma unroll
            for (int j = 0; j < 16; ++j) {
                const float4 wq = *(const float4*)(wp[j] + g * 4);
                acc[j] = fmaf(wq.x, xa.x, acc[j]);
                acc[j] = fmaf(wq.y, xa.y, acc[j]);
                acc[j] = fmaf(wq.z, xa.z, acc[j]);
                acc[j] = fmaf(wq.w, xa.w, acc[j]);
            }
        }
#pragma unroll
        for (int j = 0; j < 16; ++j) wp[j] += BK;   // advance one chunk
        __syncthreads();  // all waves done reading buf cur; next stage done
    }

    // scatter logits: lane l holds row l, experts [16*wu, 16*wu+16)
#pragma unroll
    for (int j = 0; j < 16; j += 4) {
        float4 v;
        v.x = acc[j]; v.y = acc[j + 1]; v.z = acc[j + 2]; v.w = acc[j + 3];
        *(float4*)&logits[lane][wu * 16 + j] = v;
    }
    __syncthreads();

    // epilogue: one thread per row (wave 0), identical to verified baseline
    if (t < BM) {
        const int row = r0 + t;
        float m1 = -INFINITY, m2 = -INFINITY;
        int   e1 = 0, e2 = 0;
        for (int e = 0; e < NEXP; ++e) {
            const float l = logits[t][e] + bias[e];
            if (l > m1) { m2 = m1; e2 = e1; m1 = l; e1 = e; }
            else if (l > m2) { m2 = l; e2 = e; }
        }
        float z = 0.f;
        for (int e = 0; e < NEXP; ++e)
            z += expf(logits[t][e] + bias[e] - m1);
        const float p2    = expf(m2 - m1);
        const float denom = (1.f + p2) + 1e-8f * z;
        out[row * 2 + 0] = 1.f / denom;
        out[row * 2 + 1] = p2 / denom;
        float* oidx = out + 2 * NROWS;
        oidx[row * 2 + 0] = (float)e1;
        oidx[row * 2 + 1] = (float)e2;
    }
}

extern "C" void kernel_launch(void* const* d_in, const int* in_sizes, int n_in,
                              void* d_out, int out_size, void* d_ws, size_t ws_size,
                              hipStream_t stream) {
    const float* x    = (const float*)d_in[0];   // [32768, 2048]
    const float* gw   = (const float*)d_in[1];   // [64, 2048]
    const float* bias = (const float*)d_in[2];   // [64]
    float* out = (float*)d_out;                  // 131072 floats
    (void)in_sizes; (void)n_in; (void)out_size; (void)d_ws; (void)ws_size;

    dim3 grid(NROWS / BM);   // 512 blocks -> 2 blocks/CU, 8 waves/CU
    dim3 block(256);         // 4 waves
    router_kernel<<<grid, block, 0, stream>>>(x, gw, bias, out);
}

// Round 5
// 480.166 us; speedup vs baseline: 2.0157x; 2.0157x over previous
//
#include <hip/hip_runtime.h>
#include <math.h>

#define D_MODEL 2048
#define NEXP    64
#define NROWS   32768
#define NSUB    4                  // in-block K splits
#define KSUB    (D_MODEL / NSUB)   // 512 ks per sub
#define BM      128                // rows per block
#define BKW     32                 // ks per staged W chunk
#define NCH     (KSUB / BKW)       // 16 chunks per sub
#define NG      (BKW / 4)          // 8 granules (16B) per chunk

// async global->LDS, 16B per lane; LDS dest = wave-uniform base + lane*16
__device__ __forceinline__ void stage16(const float* gsrc, void* lds_base) {
    __builtin_amdgcn_global_load_lds(
        (const __attribute__((address_space(1))) void*)gsrc,
        (__attribute__((address_space(3))) void*)lds_base,
        16, 0, 0);
}

#define FMA_TILE(XV, WV)                                        \
    _Pragma("unroll")                                           \
    for (int i = 0; i < 8; ++i) {                               \
        _Pragma("unroll")                                       \
        for (int j = 0; j < 8; ++j) {                           \
            acc[i][j] = fmaf(XV[i].x, WV[j].x, acc[i][j]);      \
            acc[i][j] = fmaf(XV[i].y, WV[j].y, acc[i][j]);      \
            acc[i][j] = fmaf(XV[i].z, WV[j].z, acc[i][j]);      \
            acc[i][j] = fmaf(XV[i].w, WV[j].w, acc[i][j]);      \
        }                                                       \
    }

// Block = 512 thr = 4 K-subs x 128 thr. Sub s computes 128 rows x 64 experts
// over k in [512s, 512s+512); 8x8 register tile per thread (rg=row-group,
// eg=expert-lane). x: DIRECT from global (dup lanes merge in TA; lines fully
// consumed -> HBM 268MB exact). W: LDS, 8 b128/granule-step (12cyc flat each
// -> ~41us total, proven flat-cost model from r0). Partials reduced in LDS.
__global__ __launch_bounds__(512, 2) void router_kernel(
    const float* __restrict__ x,      // [NROWS, D_MODEL]
    const float* __restrict__ gw,     // [NEXP, D_MODEL]
    const float* __restrict__ bias,   // [NEXP]
    float* __restrict__ out)          // [NROWS*2 weights][NROWS*2 idx-as-float]
{
    __shared__ alignas(16) float4 ws[NSUB][2][NG][NEXP]; // 64 KB W chunks
    __shared__ float logits[BM][NEXP + 1];               // 33 KB, 65-stride

    const int t    = threadIdx.x;
    const int lane = t & 63;
    const int eg   = t & 7;            // expert lane 0..7 (consecutive lanes)
    const int rg   = (t & 127) >> 3;   // row group 0..15 within sub
    const int sub  = t >> 7;           // K-split 0..3
    const int w2   = (t >> 6) & 1;     // wave within sub
    const int r0   = blockIdx.x * BM;
    const int k0   = sub * KSUB;

    // 8 row base pointers (compile-time indexed only -> stay in VGPRs)
    const float* xr[8];
#pragma unroll
    for (int i = 0; i < 8; ++i)
        xr[i] = x + (size_t)(r0 + rg * 8 + i) * D_MODEL + k0;

    float acc[8][8];
#pragma unroll
    for (int i = 0; i < 8; ++i)
#pragma unroll
        for (int j = 0; j < 8; ++j) acc[i][j] = 0.f;

    // prologue: stage chunk 0 -> buf 0 (per sub: 2 waves x 4 granule-rows)
#pragma unroll
    for (int q = 0; q < 4; ++q) {
        const int gk = w2 * 4 + q;
        stage16(gw + (size_t)lane * D_MODEL + k0 + gk * 4, &ws[sub][0][gk][0]);
    }
    __syncthreads();

    for (int c = 0; c < NCH; ++c) {
        const int cur = c & 1;
        if (c + 1 < NCH) {   // async-stage next chunk; drained by end barrier
#pragma unroll
            for (int q = 0; q < 4; ++q) {
                const int gk = w2 * 4 + q;
                stage16(gw + (size_t)lane * D_MODEL + k0 + (c + 1) * BKW + gk * 4,
                        &ws[sub][cur ^ 1][gk][0]);
            }
        }
        const int kb = c * BKW;
        // 2-granule ping-pong: named A/B sets, all indices compile-time
        float4 xa[8], wa[8], xb[8], wb[8];
#pragma unroll
        for (int i = 0; i < 8; ++i) xa[i] = *(const float4*)(xr[i] + kb);
#pragma unroll
        for (int j = 0; j < 8; ++j) wa[j] = ws[sub][cur][0][j * 8 + eg];
#pragma unroll
        for (int g = 0; g < NG; g += 2) {
            // prefetch granule g+1 into B (NG even -> g+1 always valid)
#pragma unroll
            for (int i = 0; i < 8; ++i)
                xb[i] = *(const float4*)(xr[i] + kb + (g + 1) * 4);
#pragma unroll
            for (int j = 0; j < 8; ++j)
                wb[j] = ws[sub][cur][g + 1][j * 8 + eg];
            FMA_TILE(xa, wa)
            if (g + 2 < NG) {
#pragma unroll
                for (int i = 0; i < 8; ++i)
                    xa[i] = *(const float4*)(xr[i] + kb + (g + 2) * 4);
#pragma unroll
                for (int j = 0; j < 8; ++j)
                    wa[j] = ws[sub][cur][g + 2][j * 8 + eg];
            }
            FMA_TILE(xb, wb)
        }
        __syncthreads();   // readers done with buf cur; next stage complete
    }

    // deterministic in-block K-reduction: sub 0 writes, subs 1..3 accumulate
    for (int s = 0; s < NSUB; ++s) {
        if (sub == s) {
            if (s == 0) {
#pragma unroll
                for (int i = 0; i < 8; ++i)
#pragma unroll
                    for (int j = 0; j < 8; ++j)
                        logits[rg * 8 + i][j * 8 + eg] = acc[i][j];
            } else {
#pragma unroll
                for (int i = 0; i < 8; ++i)
#pragma unroll
                    for (int j = 0; j < 8; ++j)
                        logits[rg * 8 + i][j * 8 + eg] += acc[i][j];
            }
        }
        __syncthreads();
    }

    // epilogue: one thread per row (t < 128), identical to verified baseline
    if (t < BM) {
        const int row = r0 + t;
        float m1 = -INFINITY, m2 = -INFINITY;
        int   e1 = 0, e2 = 0;
        for (int e = 0; e < NEXP; ++e) {
            const float l = logits[t][e] + bias[e];
            if (l > m1) { m2 = m1; e2 = e1; m1 = l; e1 = e; }
            else if (l > m2) { m2 = l; e2 = e; }
        }
        float z = 0.f;
        for (int e = 0; e < NEXP; ++e)
            z += expf(logits[t][e] + bias[e] - m1);
        const float p2    = expf(m2 - m1);
        const float denom = (1.f + p2) + 1e-8f * z;
        out[row * 2 + 0] = 1.f / denom;
        out[row * 2 + 1] = p2 / denom;
        float* oidx = out + 2 * NROWS;
        oidx[row * 2 + 0] = (float)e1;
        oidx[row * 2 + 1] = (float)e2;
    }
}

extern "C" void kernel_launch(void* const* d_in, const int* in_sizes, int n_in,
                              void* d_out, int out_size, void* d_ws, size_t ws_size,
                              hipStream_t stream) {
    const float* x    = (const float*)d_in[0];   // [32768, 2048]
    const float* gw   = (const float*)d_in[1];   // [64, 2048]
    const float* bias = (const float*)d_in[2];   // [64]
    float* out = (float*)d_out;                  // 131072 floats
    (void)in_sizes; (void)n_in; (void)out_size; (void)d_ws; (void)ws_size;

    dim3 grid(NROWS / BM);   // 256 blocks -> 1 block/CU, 8 waves/CU
    dim3 block(512);         // 8 waves = 4 subs x 2 waves
    router_kernel<<<grid, block, 0, stream>>>(x, gw, bias, out);
}

// Round 6
// 462.588 us; speedup vs baseline: 2.0923x; 1.0380x over previous
//
#include <hip/hip_runtime.h>
#include <math.h>

#define D_MODEL 2048
#define NEXP    64
#define NROWS   32768
#define NSUB    4                  // in-block K splits
#define KSUB    (D_MODEL / NSUB)   // 512 ks per sub
#define BM      128                // rows per block
#define BKW     32                 // ks per staged W chunk
#define NCH     (KSUB / BKW)       // 16 chunks per sub
#define NG      (BKW / 4)          // 8 granules (16B) per chunk

// async global->LDS, 16B per lane; LDS dest = wave-uniform base + lane*16
__device__ __forceinline__ void stage16(const float* gsrc, void* lds_base) {
    __builtin_amdgcn_global_load_lds(
        (const __attribute__((address_space(1))) void*)gsrc,
        (__attribute__((address_space(3))) void*)lds_base,
        16, 0, 0);
}

// Block = 512 thr = 4 K-subs x 128 thr; sub s covers k in [512s,512s+512).
// 8x8 register tile (rg=row-group, eg=expert-lane). x: DIRECT global loads
// (8 dup eg-lanes merge in TA; offsets fold into 13-bit imm). W: LDS via
// global_load_lds, 8 b128/granule -> ~41us LDS (flat 12cyc/b128 model,
// calibrated r0). NO manual ping-pong: r5 proved it forces a ~208-float
// live set that the allocator (self-capped at 128) spills to scratch
// (WRITE_SIZE 7.7MB). waves_per_eu(2,2) pins the budget at 256 VGPR so the
// compiler pipelines within registers instead.
__global__
__attribute__((amdgpu_flat_work_group_size(512, 512)))
__attribute__((amdgpu_waves_per_eu(2, 2)))
void router_kernel(
    const float* __restrict__ x,      // [NROWS, D_MODEL]
    const float* __restrict__ gw,     // [NEXP, D_MODEL]
    const float* __restrict__ bias,   // [NEXP]
    float* __restrict__ out)          // [NROWS*2 weights][NROWS*2 idx-as-float]
{
    __shared__ alignas(16) float4 ws[NSUB][2][NG][NEXP]; // 64 KB W chunks
    __shared__ float logits[BM][NEXP + 1];               // 33 KB, 65-stride

    const int t    = threadIdx.x;
    const int lane = t & 63;
    const int eg   = t & 7;            // expert lane 0..7 (consecutive lanes)
    const int rg   = (t & 127) >> 3;   // row group 0..15 within sub
    const int sub  = t >> 7;           // K-split 0..3
    const int w2   = (t >> 6) & 1;     // wave within sub
    const int r0   = blockIdx.x * BM;
    const int k0   = sub * KSUB;

    // 8 row base pointers (compile-time indexed only -> stay in VGPRs)
    const float* xr[8];
#pragma unroll
    for (int i = 0; i < 8; ++i)
        xr[i] = x + (size_t)(r0 + rg * 8 + i) * D_MODEL + k0;

    float acc[8][8];
#pragma unroll
    for (int i = 0; i < 8; ++i)
#pragma unroll
        for (int j = 0; j < 8; ++j) acc[i][j] = 0.f;

    // prologue: stage chunk 0 -> buf 0 (per sub: 2 waves x 4 granule-rows;
    // lane = expert index, so LDS [gk][lane] gets W[lane][k0+gk*4..+4))
#pragma unroll
    for (int q = 0; q < 4; ++q) {
        const int gk = w2 * 4 + q;
        stage16(gw + (size_t)lane * D_MODEL + k0 + gk * 4, &ws[sub][0][gk][0]);
    }
    __syncthreads();

    for (int c = 0; c < NCH; ++c) {
        const int cur = c & 1;
        if (c + 1 < NCH) {   // async-stage next chunk; drained by end barrier
#pragma unroll
            for (int q = 0; q < 4; ++q) {
                const int gk = w2 * 4 + q;
                stage16(gw + (size_t)lane * D_MODEL + k0 + (c + 1) * BKW + gk * 4,
                        &ws[sub][cur ^ 1][gk][0]);
            }
        }
        const int kb = c * BKW;
#pragma unroll
        for (int g = 0; g < NG; ++g) {
            // 8 rows x 4 ks direct from global (L1-resident lines, imm offsets)
            float4 xv[8];
#pragma unroll
            for (int i = 0; i < 8; ++i)
                xv[i] = *(const float4*)(xr[i] + kb + g * 4);
            // 8 experts x 4 ks from LDS (lanes eg=0..7 -> consecutive 16B)
            float4 wv[8];
#pragma unroll
            for (int j = 0; j < 8; ++j)
                wv[j] = ws[sub][cur][g][j * 8 + eg];
#pragma unroll
            for (int i = 0; i < 8; ++i) {
#pragma unroll
                for (int j = 0; j < 8; ++j) {
                    acc[i][j] = fmaf(xv[i].x, wv[j].x, acc[i][j]);
                    acc[i][j] = fmaf(xv[i].y, wv[j].y, acc[i][j]);
                    acc[i][j] = fmaf(xv[i].z, wv[j].z, acc[i][j]);
                    acc[i][j] = fmaf(xv[i].w, wv[j].w, acc[i][j]);
                }
            }
        }
        __syncthreads();   // readers done with buf cur; next stage complete
    }

    // deterministic in-block K-reduction: sub 0 writes, subs 1..3 accumulate
    for (int s = 0; s < NSUB; ++s) {
        if (sub == s) {
            if (s == 0) {
#pragma unroll
                for (int i = 0; i < 8; ++i)
#pragma unroll
                    for (int j = 0; j < 8; ++j)
                        logits[rg * 8 + i][j * 8 + eg] = acc[i][j];
            } else {
#pragma unroll
                for (int i = 0; i < 8; ++i)
#pragma unroll
                    for (int j = 0; j < 8; ++j)
                        logits[rg * 8 + i][j * 8 + eg] += acc[i][j];
            }
        }
        __syncthreads();
    }

    // epilogue: one thread per row (t < 128), identical to verified baseline
    if (t < BM) {
        const int row = r0 + t;
        float m1 = -INFINITY, m2 = -INFINITY;
        int   e1 = 0, e2 = 0;
        for (int e = 0; e < NEXP; ++e) {
            const float l = logits[t][e] + bias[e];
            if (l > m1) { m2 = m1; e2 = e1; m1 = l; e1 = e; }
            else if (l > m2) { m2 = l; e2 = e; }
        }
        float z = 0.f;
        for (int e = 0; e < NEXP; ++e)
            z += expf(logits[t][e] + bias[e] - m1);
        const float p2    = expf(m2 - m1);
        const float denom = (1.f + p2) + 1e-8f * z;
        out[row * 2 + 0] = 1.f / denom;
        out[row * 2 + 1] = p2 / denom;
        float* oidx = out + 2 * NROWS;
        oidx[row * 2 + 0] = (float)e1;
        oidx[row * 2 + 1] = (float)e2;
    }
}

extern "C" void kernel_launch(void* const* d_in, const int* in_sizes, int n_in,
                              void* d_out, int out_size, void* d_ws, size_t ws_size,
                              hipStream_t stream) {
    const float* x    = (const float*)d_in[0];   // [32768, 2048]
    const float* gw   = (const float*)d_in[1];   // [64, 2048]
    const float* bias = (const float*)d_in[2];   // [64]
    float* out = (float*)d_out;                  // 131072 floats
    (void)in_sizes; (void)n_in; (void)out_size; (void)d_ws; (void)ws_size;

    dim3 grid(NROWS / BM);   // 256 blocks -> 1 block/CU, 8 waves/CU
    dim3 block(512);         // 8 waves = 4 subs x 2 waves
    router_kernel<<<grid, block, 0, stream>>>(x, gw, bias, out);
}